// Round 3
// baseline (551.497 us; speedup 1.0000x reference)
//
#include <hip/hip_runtime.h>
#include <math.h>

// Problem constants (SwinTransformerBlock: B=16,H=W=64,E=32,WD=8 -> NW=64,D=2048)
#define ROWS 1024          // B*NW
#define DIM  2048
#define FFDIM 8192
#define NHEAD 8
#define HD 256             // DIM/NHEAD
#define NWIN 64

typedef __attribute__((ext_vector_type(8))) short short8;   // 8 bf16 (4 VGPRs)
typedef __attribute__((ext_vector_type(4))) float f32x4;
typedef unsigned int uint32;

#define MFMA16(a, b, c) __builtin_amdgcn_mfma_f32_16x16x32_bf16((a), (b), (c), 0, 0, 0)

// truncate-to-bf16 split helpers: x = hi + lo
__device__ __forceinline__ uint32 pack_hi2(float a, float b) {
  return (__float_as_uint(a) >> 16) | (__float_as_uint(b) & 0xFFFF0000u);
}
__device__ __forceinline__ float trunc_hi(float a) {
  return __uint_as_float(__float_as_uint(a) & 0xFFFF0000u);
}
// 16B-slot XOR swizzle within a 64B LDS row: conflict-free (<=2-way) b128 access
#define SWZ(r) (((r) >> 1) & 3)

// ---------------------------------------------------------------------------
// Split-bf16 MFMA GEMM body. C[M,N](partial) = A[M,K(kbeg:kend)] @ W + epi.
// Block: 256 threads = 4 waves (2x2). Tile: BM = MI*32 rows x 128 cols, BK=32.
// LDS tiles: X[row][k] bf16, row stride 64B, slot-swizzled. A rows=m, B rows=n.
// EPI: 0 none, 1 exact GELU, 2 +residual R, 3 raw partial (no bias)
template <int MI, int EPI>
__device__ __forceinline__ void gemm_body(
    const float* __restrict__ A, const float* __restrict__ W,
    const float* __restrict__ bias, const float* __restrict__ R,
    float* __restrict__ C, int N, int K, int kbeg, int kend, int m0, int n0,
    short* Ah, short* Al, short* Bh, short* Bl) {
  const int t = threadIdx.x;
  const int lane = t & 63;
  const int wid = t >> 6;
  const int wr = wid >> 1, wc = wid & 1;
  const int l15 = lane & 15, l4 = lane >> 4;

  // staging thread mapping
  const int arow = t >> 3, akq = t & 7;   // A: rows (t>>3)+32*it, float4 #akq
  const int bn = t & 127, bkc = t >> 7;   // B: col bn, k-chunk bkc (16 k each)

  f32x4 acc[MI][4];
#pragma unroll
  for (int i = 0; i < MI; ++i)
#pragma unroll
    for (int j = 0; j < 4; ++j) {
      f32x4 z = {0.f, 0.f, 0.f, 0.f};
      acc[i][j] = z;
    }

  // per-lane fragment LDS byte offsets (loop-invariant)
  int aoff[MI], boff[4];
#pragma unroll
  for (int mi = 0; mi < MI; ++mi) {
    int m = wr * MI * 16 + mi * 16 + l15;      // frag row = lane&15
    aoff[mi] = m * 64 + ((l4 ^ SWZ(m)) << 4);  // k-slot = lane>>4 (8 bf16)
  }
#pragma unroll
  for (int ni = 0; ni < 4; ++ni) {
    int n = wc * 64 + ni * 16 + l15;
    boff[ni] = n * 64 + ((l4 ^ SWZ(n)) << 4);
  }

  const float* aptr = A + (size_t)(m0 + arow) * K + akq * 4;
  const float* bptr = W + (size_t)bkc * 16 * N + n0 + bn;

  // ---- prologue: load first tile into regs ----
  float4 av[MI];
  float bv[16];
#pragma unroll
  for (int it = 0; it < MI; ++it)
    av[it] = *(const float4*)(aptr + (size_t)(it * 32) * K + kbeg);
#pragma unroll
  for (int i = 0; i < 16; ++i)
    bv[i] = bptr[(size_t)(kbeg + i) * N];   // coalesced across lanes

  for (int k0 = kbeg; k0 < kend; k0 += 32) {
    __syncthreads();   // previous tile's fragment reads done

    // ---- A tile: convert + swizzled write (waits vmcnt for av/bv) ----
#pragma unroll
    for (int it = 0; it < MI; ++it) {
      const int row = arow + it * 32;
      const int off = row * 64 + (((akq >> 1) ^ SWZ(row)) << 4) + (akq & 1) * 8;
      const float x = av[it].x, y = av[it].y, z = av[it].z, w = av[it].w;
      uint32 h0 = pack_hi2(x, y), h1 = pack_hi2(z, w);
      uint32 L0 = pack_hi2(x - trunc_hi(x), y - trunc_hi(y));
      uint32 L1 = pack_hi2(z - trunc_hi(z), w - trunc_hi(w));
      *(uint2*)((char*)Ah + off) = make_uint2(h0, h1);
      *(uint2*)((char*)Al + off) = make_uint2(L0, L1);
    }
    // ---- B tile: transpose-in-regs, convert + swizzled write ----
    {
      uint32 hh[8], ll[8];
#pragma unroll
      for (int j = 0; j < 8; ++j) {
        const float a = bv[2 * j], b = bv[2 * j + 1];
        hh[j] = pack_hi2(a, b);
        ll[j] = pack_hi2(a - trunc_hi(a), b - trunc_hi(b));
      }
      const int s0 = bn * 64 + (((bkc * 2) ^ SWZ(bn)) << 4);
      const int s1 = bn * 64 + (((bkc * 2 + 1) ^ SWZ(bn)) << 4);
      *(uint4*)((char*)Bh + s0) = make_uint4(hh[0], hh[1], hh[2], hh[3]);
      *(uint4*)((char*)Bh + s1) = make_uint4(hh[4], hh[5], hh[6], hh[7]);
      *(uint4*)((char*)Bl + s0) = make_uint4(ll[0], ll[1], ll[2], ll[3]);
      *(uint4*)((char*)Bl + s1) = make_uint4(ll[4], ll[5], ll[6], ll[7]);
    }
    __syncthreads();   // tile ready

    // ---- issue NEXT tile's global loads (latency hides under MFMA) ----
    if (k0 + 32 < kend) {
#pragma unroll
      for (int it = 0; it < MI; ++it)
        av[it] = *(const float4*)(aptr + (size_t)(it * 32) * K + (k0 + 32));
#pragma unroll
      for (int i = 0; i < 16; ++i)
        bv[i] = bptr[(size_t)(k0 + 32 + i) * N];
    }

    // ---- fragment reads + 3-term MFMA ----
    short8 ah[MI], al[MI], bh[4], bl[4];
#pragma unroll
    for (int mi = 0; mi < MI; ++mi) {
      ah[mi] = *(const short8*)((const char*)Ah + aoff[mi]);
      al[mi] = *(const short8*)((const char*)Al + aoff[mi]);
    }
#pragma unroll
    for (int ni = 0; ni < 4; ++ni) {
      bh[ni] = *(const short8*)((const char*)Bh + boff[ni]);
      bl[ni] = *(const short8*)((const char*)Bl + boff[ni]);
    }
#pragma unroll
    for (int mi = 0; mi < MI; ++mi)
#pragma unroll
      for (int ni = 0; ni < 4; ++ni) {
        acc[mi][ni] = MFMA16(ah[mi], bh[ni], acc[mi][ni]);
        acc[mi][ni] = MFMA16(ah[mi], bl[ni], acc[mi][ni]);
        acc[mi][ni] = MFMA16(al[mi], bh[ni], acc[mi][ni]);
      }
  }

  // ---- epilogue: C row = (lane>>4)*4 + r, col = lane&15 ----
#pragma unroll
  for (int ni = 0; ni < 4; ++ni) {
    const int n = n0 + wc * 64 + ni * 16 + l15;
    const float bb = (EPI == 3) ? 0.f : bias[n];
#pragma unroll
    for (int mi = 0; mi < MI; ++mi) {
      const int mbase = m0 + wr * MI * 16 + mi * 16 + l4 * 4;
#pragma unroll
      for (int r = 0; r < 4; ++r) {
        float x = acc[mi][ni][r] + bb;
        const size_t idx = (size_t)(mbase + r) * N + n;
        if (EPI == 1) {
          x = 0.5f * x * (1.0f + erff(x * 0.70710678118654752f));
        } else if (EPI == 2) {
          x += R[idx];
        }
        C[idx] = x;
      }
    }
  }
}

// ksplit: K-range per z-slice (== K when gridDim.z == 1).
// For EPI==3, C is a partial buffer of gridDim.z slices of ROWS*N each.
template <int MI, int EPI>
__global__ __launch_bounds__(256, 2)
void gemm_k(const float* __restrict__ A, const float* __restrict__ W,
            const float* __restrict__ bias, const float* __restrict__ R,
            float* __restrict__ C, int N, int K, int ksplit) {
  __shared__ short Ah[MI * 1024], Al[MI * 1024], Bh[4096], Bl[4096];
  const int kbeg = blockIdx.z * ksplit;
  float* Ceff = C + (size_t)blockIdx.z * ROWS * N;
  gemm_body<MI, EPI>(A, W, bias, R, Ceff, N, K, kbeg, kbeg + ksplit,
                     blockIdx.y * MI * 32, blockIdx.x * 128, Ah, Al, Bh, Bl);
}

// QKV fused: grid.x = 48 (3 matrices x 16 col-blocks), shares A tile pattern.
__global__ __launch_bounds__(256, 2)
void qkv_k(const float* __restrict__ A,
           const float* __restrict__ wq, const float* __restrict__ bq,
           const float* __restrict__ wk, const float* __restrict__ bk,
           const float* __restrict__ wv, const float* __restrict__ bv,
           float* __restrict__ q) {
  __shared__ short Ah[4096], Al[4096], Bh[4096], Bl[4096];
  const int nb = blockIdx.x;
  const int mat = nb >> 4;
  const float* W = (mat == 0) ? wq : (mat == 1) ? wk : wv;
  const float* B = (mat == 0) ? bq : (mat == 1) ? bk : bv;
  float* out = q + (size_t)mat * ROWS * DIM;
  gemm_body<4, 0>(A, W, B, nullptr, out, DIM, DIM, 0, DIM, blockIdx.y * 128,
                  (nb & 15) * 128, Ah, Al, Bh, Bl);
}

// split-K reduce for FFN2: out = sum_s p[s] + bias + R
__global__ __launch_bounds__(256)
void reduce4_kernel(const float* __restrict__ p, const float* __restrict__ bias,
                    const float* __restrict__ R, float* __restrict__ out) {
  const int idx = blockIdx.x * 256 + threadIdx.x;       // float4 index
  const size_t PS = (size_t)ROWS * DIM / 4;
  const float4* p4 = (const float4*)p;
  float4 s0 = p4[idx], s1 = p4[idx + PS], s2 = p4[idx + 2 * PS], s3 = p4[idx + 3 * PS];
  const int n = (idx & (DIM / 4 - 1)) * 4;
  float4 bi = *(const float4*)&bias[n];
  float4 rr = ((const float4*)R)[idx];
  float4 o;
  o.x = s0.x + s1.x + s2.x + s3.x + bi.x + rr.x;
  o.y = s0.y + s1.y + s2.y + s3.y + bi.y + rr.y;
  o.z = s0.z + s1.z + s2.z + s3.z + bi.z + rr.z;
  o.w = s0.w + s1.w + s2.w + s3.w + bi.w + rr.w;
  ((float4*)out)[idx] = o;
}

// ---------------------------------------------------------------------------
// Block-wide mean/rstd over 2048 elements (256 threads, 8 elems each)
__device__ inline void block_stats(float s, float ss, float& mean, float& rstd) {
#pragma unroll
  for (int off = 32; off; off >>= 1) {
    s  += __shfl_xor(s,  off);
    ss += __shfl_xor(ss, off);
  }
  __shared__ float red[8];
  const int t = threadIdx.x;
  const int w = t >> 6;
  if ((t & 63) == 0) { red[w] = s; red[4 | w] = ss; }
  __syncthreads();
  s  = red[0] + red[1] + red[2] + red[3];
  ss = red[4] + red[5] + red[6] + red[7];
  mean = s * (1.0f / DIM);
  float var = ss * (1.0f / DIM) - mean * mean;
  rstd = 1.0f / sqrtf(var + 1e-5f);
}

// ---------------------------------------------------------------------------
// Kernel 1: window partition gather + LN1. One block per window-row.
// windows[row][d], row=b*64+vw*8+hw, d=(vp*8+hp)*32+e <- emb[b][vp*8+vw][hp*8+hw][e]
__global__ __launch_bounds__(256)
void partition_ln1_kernel(const float* __restrict__ emb,
                          const float* __restrict__ g, const float* __restrict__ be,
                          float* __restrict__ windows, float* __restrict__ xln) {
  const int row = blockIdx.x;
  const int b = row >> 6, n = row & 63;
  const int vw = n >> 3, hw = n & 7;
  const int t = threadIdx.x;
  const int d0 = t * 4, d1 = d0 + 1024;

  const int vp0 = d0 >> 8, hp0 = (d0 >> 5) & 7, e0 = d0 & 31;
  const int vp1 = d1 >> 8, hp1 = (d1 >> 5) & 7, e1 = d1 & 31;
  float4 v0 = *(const float4*)&emb[(size_t)(((b*64 + vp0*8 + vw)*64) + hp0*8 + hw)*32 + e0];
  float4 v1 = *(const float4*)&emb[(size_t)(((b*64 + vp1*8 + vw)*64) + hp1*8 + hw)*32 + e1];

  float s  = v0.x+v0.y+v0.z+v0.w + v1.x+v1.y+v1.z+v1.w;
  float ss = v0.x*v0.x+v0.y*v0.y+v0.z*v0.z+v0.w*v0.w
           + v1.x*v1.x+v1.y*v1.y+v1.z*v1.z+v1.w*v1.w;
  float mean, rstd;
  block_stats(s, ss, mean, rstd);

  float* wrow = windows + (size_t)row * DIM;
  *(float4*)&wrow[d0] = v0;
  *(float4*)&wrow[d1] = v1;

  float4 g0 = *(const float4*)&g[d0],  g1 = *(const float4*)&g[d1];
  float4 b0 = *(const float4*)&be[d0], b1 = *(const float4*)&be[d1];
  float4 o0, o1;
  o0.x = (v0.x-mean)*rstd*g0.x + b0.x; o0.y = (v0.y-mean)*rstd*g0.y + b0.y;
  o0.z = (v0.z-mean)*rstd*g0.z + b0.z; o0.w = (v0.w-mean)*rstd*g0.w + b0.w;
  o1.x = (v1.x-mean)*rstd*g1.x + b1.x; o1.y = (v1.y-mean)*rstd*g1.y + b1.y;
  o1.z = (v1.z-mean)*rstd*g1.z + b1.z; o1.w = (v1.w-mean)*rstd*g1.w + b1.w;
  float* xrow = xln + (size_t)row * DIM;
  *(float4*)&xrow[d0] = o0;
  *(float4*)&xrow[d1] = o1;
}

// ---------------------------------------------------------------------------
// Generic row LayerNorm (LN2). One block per row.
__global__ __launch_bounds__(256)
void ln_kernel(const float* __restrict__ in, const float* __restrict__ g,
               const float* __restrict__ be, float* __restrict__ out) {
  const int row = blockIdx.x;
  const int t = threadIdx.x;
  const float* x = in + (size_t)row * DIM;
  const int d0 = t * 4, d1 = d0 + 1024;
  float4 v0 = *(const float4*)&x[d0];
  float4 v1 = *(const float4*)&x[d1];
  float s  = v0.x+v0.y+v0.z+v0.w + v1.x+v1.y+v1.z+v1.w;
  float ss = v0.x*v0.x+v0.y*v0.y+v0.z*v0.z+v0.w*v0.w
           + v1.x*v1.x+v1.y*v1.y+v1.z*v1.z+v1.w*v1.w;
  float mean, rstd;
  block_stats(s, ss, mean, rstd);
  float4 g0 = *(const float4*)&g[d0],  g1 = *(const float4*)&g[d1];
  float4 b0 = *(const float4*)&be[d0], b1 = *(const float4*)&be[d1];
  float4 o0, o1;
  o0.x = (v0.x-mean)*rstd*g0.x + b0.x; o0.y = (v0.y-mean)*rstd*g0.y + b0.y;
  o0.z = (v0.z-mean)*rstd*g0.z + b0.z; o0.w = (v0.w-mean)*rstd*g0.w + b0.w;
  o1.x = (v1.x-mean)*rstd*g1.x + b1.x; o1.y = (v1.y-mean)*rstd*g1.y + b1.y;
  o1.z = (v1.z-mean)*rstd*g1.z + b1.z; o1.w = (v1.w-mean)*rstd*g1.w + b1.w;
  float* orow = out + (size_t)row * DIM;
  *(float4*)&orow[d0] = o0;
  *(float4*)&orow[d1] = o1;
}

// ---------------------------------------------------------------------------
// Attention: one block per (b, head, query-half). 32 queries x 64 keys x hd=256.
// 256 blocks -> 1 per CU. Q staged coalesced into padded LDS.
__global__ __launch_bounds__(256)
void attn_kernel(const float* __restrict__ Q, const float* __restrict__ K,
                 const float* __restrict__ V, const float* __restrict__ pb,
                 const float* __restrict__ windows, float* __restrict__ attn_out) {
  __shared__ float kv[NWIN][HD];       // 64KB: K then reused for V
  __shared__ float qs[32][HD + 4];     // 32.5KB, padded (+4) for row reads
  __shared__ float att[32][NWIN + 1];  // 8.1KB
  const int blk = blockIdx.x;
  const int bh = blk >> 1, half = blk & 1;
  const int b = bh >> 3, h = bh & 7;
  const int qbase = half * 32;
  const int t = threadIdx.x;
  const size_t base = (size_t)b * 64 * DIM + (size_t)h * HD;

  // load K slice [64][256] (coalesced) and Q half [32][256]
#pragma unroll
  for (int j = 0; j < 16; ++j) {
    int idx = t + j * 256;               // float4 index
    int m = idx >> 6, dg = idx & 63;
    *(float4*)&kv[m][dg * 4] = *(const float4*)&K[base + (size_t)m * DIM + dg * 4];
  }
#pragma unroll
  for (int j = 0; j < 8; ++j) {
    int idx = t + j * 256;
    int m = idx >> 6, dg = idx & 63;
    *(float4*)&qs[m][dg * 4] = *(const float4*)&Q[base + (size_t)(qbase + m) * DIM + dg * 4];
  }
  __syncthreads();

  // logits: thread -> q-row n = t&31, 8 keys m in [(t>>5)*8, +8)
  {
    const int n = t & 31;
    const int m0 = (t >> 5) * 8;
    float acc[8];
#pragma unroll
    for (int j = 0; j < 8; ++j) acc[j] = 0.f;
    for (int dg = 0; dg < 64; ++dg) {
      float4 qv = *(const float4*)&qs[n][dg * 4];
#pragma unroll
      for (int j = 0; j < 8; ++j) {
        const float* kr = &kv[m0 + j][dg * 4];
        acc[j] += qv.x * kr[0] + qv.y * kr[1] + qv.z * kr[2] + qv.w * kr[3];
      }
    }
    const float scale = 0.022097086912079608f;  // 1/sqrt(2048)
#pragma unroll
    for (int j = 0; j < 8; ++j) {
      const int m = m0 + j;
      float l = acc[j] * scale + pb[(qbase + n) * 64 + m];
      if (m == qbase + n) l = -INFINITY;
      att[n][m] = l;
    }
  }
  __syncthreads();

  // V load (all threads) overlapped with softmax (threads < 32)
#pragma unroll
  for (int j = 0; j < 16; ++j) {
    int idx = t + j * 256;
    int m = idx >> 6, dg = idx & 63;
    *(float4*)&kv[m][dg * 4] = *(const float4*)&V[base + (size_t)m * DIM + dg * 4];
  }
  if (t < 32) {
    float mx = -INFINITY;
#pragma unroll
    for (int m = 0; m < 64; ++m) mx = fmaxf(mx, att[t][m]);
    float sum = 0.f;
#pragma unroll
    for (int m = 0; m < 64; ++m) {
      float e = expf(att[t][m] - mx);
      att[t][m] = e;
      sum += e;
    }
    float inv = 1.0f / sum;
#pragma unroll
    for (int m = 0; m < 64; ++m) att[t][m] *= inv;
  }
  __syncthreads();

  // PV + residual: thread -> d-group dg=t&63 (4 floats), rows (t>>6)*8..+8
  {
    const int dg = t & 63, nh = t >> 6;
#pragma unroll
    for (int i = 0; i < 8; ++i) {
      const int nn = nh * 8 + i;
      float4 s = make_float4(0.f, 0.f, 0.f, 0.f);
      for (int m = 0; m < 64; ++m) {
        const float a = att[nn][m];
        const float* vr = &kv[m][dg * 4];
        s.x = fmaf(a, vr[0], s.x); s.y = fmaf(a, vr[1], s.y);
        s.z = fmaf(a, vr[2], s.z); s.w = fmaf(a, vr[3], s.w);
      }
      const size_t o = base + (size_t)(qbase + nn) * DIM + dg * 4;
      float4 w4 = *(const float4*)&windows[o];
      s.x += w4.x; s.y += w4.y; s.z += w4.z; s.w += w4.w;
      *(float4*)&attn_out[o] = s;
    }
  }
}

// ---------------------------------------------------------------------------
extern "C" void kernel_launch(void* const* d_in, const int* in_sizes, int n_in,
                              void* d_out, int out_size, void* d_ws, size_t ws_size,
                              hipStream_t stream) {
  const float* emb  = (const float*)d_in[0];
  const float* ln1g = (const float*)d_in[1];
  const float* ln1b = (const float*)d_in[2];
  const float* wq   = (const float*)d_in[3];
  const float* bq   = (const float*)d_in[4];
  const float* wk   = (const float*)d_in[5];
  const float* bk   = (const float*)d_in[6];
  const float* wv   = (const float*)d_in[7];
  const float* bv   = (const float*)d_in[8];
  const float* pb   = (const float*)d_in[9];
  const float* ln2g = (const float*)d_in[10];
  const float* ln2b = (const float*)d_in[11];
  const float* w1   = (const float*)d_in[12];
  const float* b1   = (const float*)d_in[13];
  const float* w2   = (const float*)d_in[14];
  const float* b2   = (const float*)d_in[15];
  float* out = (float*)d_out;

  // workspace layout (floats). total 10*OFF*4B = 80 MB.
  float* ws = (float*)d_ws;
  const size_t OFF = (size_t)ROWS * DIM;   // 2M floats
  float* windows  = ws;                    // OFF0 (dead after attn)
  float* xln      = ws + OFF;              // OFF1 (LN1 out, then LN2 out)
  float* q        = ws + 2 * OFF;          // OFF2..4: q,k,v (dead after attn)
  float* attn_out = ws + 5 * OFF;          // OFF5 (live to the end)
  float* ffh      = ws + 6 * OFF;          // OFF6..9: 1024x8192
  float* partial  = ws;                    // OFF0..3 reused for FFN2 split-K

  partition_ln1_kernel<<<ROWS, 256, 0, stream>>>(emb, ln1g, ln1b, windows, xln);

  // fused QKV: 3x [1024,2048]x[2048,2048], 384 blocks
  qkv_k<<<dim3(48, 8), 256, 0, stream>>>(xln, wq, bq, wk, bk, wv, bv, q);

  // 256 blocks: (b, head, query-half)
  attn_kernel<<<16 * NHEAD * 2, 256, 0, stream>>>(q, q + OFF, q + 2 * OFF, pb,
                                                  windows, attn_out);

  ln_kernel<<<ROWS, 256, 0, stream>>>(attn_out, ln2g, ln2b, xln);

  // FFN1: [1024,2048]x[2048,8192] + GELU, 512 blocks (2/CU)
  gemm_k<4, 1><<<dim3(FFDIM / 128, ROWS / 128, 1), 256, 0, stream>>>(
      xln, w1, b1, nullptr, ffh, FFDIM, DIM, DIM);
  // FFN2: [1024,8192]x[8192,2048], split-K=4 -> 512 blocks (2/CU), raw partials
  gemm_k<4, 3><<<dim3(DIM / 128, ROWS / 128, 4), 256, 0, stream>>>(
      ffh, w2, nullptr, nullptr, partial, DIM, FFDIM, FFDIM / 4);
  // reduce: out = sum(partials) + b2 + attn_out
  reduce4_kernel<<<(ROWS * DIM / 4) / 256, 256, 0, stream>>>(partial, b2, attn_out, out);
}